// Round 5
// baseline (95.785 us; speedup 1.0000x reference)
//
#include <hip/hip_runtime.h>
#include <math.h>

#define B_   2
#define C_   3
#define HW_  1024
#define N_   4096
#define AC_  12
#define JSPLIT 16
#define JTILE  256
#define ROWBLK 128
#define MAINBLKS 512            // 32 rowblks * 16 jblks
#define CPBLKS   40             // copy blocks per b (y-dim)
#define PI_F 3.14159265358979323846f
#define L2E     1.4426950408889634f   // log2(e)
#define INV_L2E 0.6931471805599453f   // ln(2)

#define OUT0_ELEMS 24576   // B*A*C*H*W
#define OUT1_ELEMS 57344   // B*A*7*H*W
#define OUT2_ELEMS 18432   // B*C*3*H*W

#define CP_F4_BBOX 14336        // OUT1_ELEMS/4
#define CP_F4_TOT  18944        // (OUT1+OUT2)/4
#define CP_F4_HALF 9472         // per-b half

// ws layout (float units): partials only.
//   part: float2[2][16][3][4096]  @ 0   (786432 floats, ~3.1 MB)
#define WS_PART  0

#if __has_builtin(__builtin_amdgcn_exp2f)
#define EXP2F(x) __builtin_amdgcn_exp2f(x)
#else
#define EXP2F(x) __expf((x) * INV_L2E)
#endif

// Decode one row of `decoded` into a BEV corner box (x1,y1,x2,y2).
__device__ __forceinline__ float4 make_box(const float* __restrict__ d) {
    float x = d[0], y = d[1], d3 = d[3], d4 = d[4], rot = d[6];
    float kq = floorf(rot / PI_F + 0.5f);
    float normed = fabsf(rot - kq * PI_F);
    bool swap_wh = normed > (0.25f * PI_F);
    float w = swap_wh ? d4 : d3;
    float h = swap_wh ? d3 : d4;
    return make_float4(x - 0.5f * w, y - 0.5f * h, x + 0.5f * w, y + 0.5f * h);
}

// grid (512 + CPBLKS, B_), 256 threads.
// blocks [0,512): 128 rows x 256 j's of batch b, ALL 3 CLASSES at once —
//   IoU core (incl. v_rcp) computed once per (i,j), shared across classes.
//   Block self-stages its j-tile and row data straight from raw inputs
//   (one-time ~60 ops/thread; x48 redundant input reads are L2 hits).
// blocks [512, 512+CPBLKS): passthrough copies of outputs 1+2, split by b.
// Softmax max-shifts dropped: they cancel in num/(den*S); values safe in f32.
// Union EPS clamp dropped: dims in [0.5,4.5] -> union >= 0.25 >> 1e-6.
__global__ __launch_bounds__(256) void k_main(
    const float* __restrict__ scores, const float* __restrict__ pp,
    const float* __restrict__ dec, const float* __restrict__ bbox,
    float* __restrict__ ws, float* __restrict__ out)
{
    const int b = blockIdx.y;
    const int bx = blockIdx.x;
    const int t = threadIdx.x;

    if (bx >= MAINBLKS) {
        // ---- passthrough copy blocks (fill CU bubbles during compute) ----
        const int u = (bx - MAINBLKS) * 256 + t;
        if (u < CP_F4_HALF) {
            const int g = b * CP_F4_HALF + u;
            if (g < CP_F4_BBOX)
                ((float4*)(out + OUT0_ELEMS))[g] = ((const float4*)bbox)[g];
            else
                ((float4*)(out + OUT0_ELEMS + OUT1_ELEMS))[g - CP_F4_BBOX] =
                    ((const float4*)pp)[g - CP_F4_BBOX];
        }
        return;
    }

    const int jb = bx & 15, rowblk = bx >> 4;
    const int q = t >> 6;   // wave index == j-quarter
    const int r = t & 63;
    const float* decb = dec + b * N_ * 7;

    __shared__ float4 s_box[JTILE];
    __shared__ float4 s_aux[JTILE];
    __shared__ float4 s_p1[JTILE];
    __shared__ float2 s_m[C_][ROWBLK][4];

    // ---- self-stage j-tile: thread t owns j = jb*256 + t ----
    {
        const int j = jb * JTILE + t;
        const int hw = j >> 2, a = j & 3;
        float4 box = make_box(decb + j * 7);
        float area = (box.z - box.x) * (box.w - box.y);
        float e0 = __expf(scores[(b * AC_ + a * C_ + 0) * HW_ + hw]);
        float e1 = __expf(scores[(b * AC_ + a * C_ + 1) * HW_ + hw]);
        float e2 = __expf(scores[(b * AC_ + a * C_ + 2) * HW_ + hw]);
        s_box[t] = box;
        s_aux[t] = make_float4(area * INV_L2E, e0, e1, e2);
        s_p1[t]  = make_float4(pp[(b * 9 + 1) * HW_ + hw],
                               pp[(b * 9 + 4) * HW_ + hw],
                               pp[(b * 9 + 7) * HW_ + hw], 0.f);
    }

    // ---- self-stage row data: thread owns rows i0, i0+64 ----
    const int i0 = rowblk * ROWBLK + r, i1 = i0 + 64;
    const float4 bx0 = make_box(decb + i0 * 7);
    const float4 bx1 = make_box(decb + i1 * 7);
    const float ar0 = (bx0.z - bx0.x) * (bx0.w - bx0.y) * INV_L2E;
    const float ar1 = (bx1.z - bx1.x) * (bx1.w - bx1.y) * INV_L2E;
    const int hw0 = i0 >> 2, hw1 = i1 >> 2;
    const float4 p0v0 = make_float4(pp[(b * 9 + 0) * HW_ + hw0] * L2E,
                                    pp[(b * 9 + 3) * HW_ + hw0] * L2E,
                                    pp[(b * 9 + 6) * HW_ + hw0] * L2E, 0.f);
    const float4 p0v1 = make_float4(pp[(b * 9 + 0) * HW_ + hw1] * L2E,
                                    pp[(b * 9 + 3) * HW_ + hw1] * L2E,
                                    pp[(b * 9 + 6) * HW_ + hw1] * L2E, 0.f);

    __syncthreads();

    float n00 = 0.f, d00 = 0.f, n01 = 0.f, d01 = 0.f, n02 = 0.f, d02 = 0.f;
    float n10 = 0.f, d10 = 0.f, n11 = 0.f, d11 = 0.f, n12 = 0.f, d12 = 0.f;

#pragma unroll 4
    for (int jj = q; jj < JTILE; jj += 4) {
        const float4 bj = s_box[jj];
        const float4 ax = s_aux[jj];   // {area_j*ln2, e0, e1, e2}
        const float4 pj = s_p1[jj];    // {p1_0, p1_1, p1_2, -}
        {   // row 0: shared IoU, 3-class tail
            float x1 = fmaxf(bx0.x, bj.x), y1 = fmaxf(bx0.y, bj.y);
            float x2 = fminf(bx0.z, bj.z), y2 = fminf(bx0.w, bj.w);
            float w = fmaxf(x2 - x1, 0.f), h = fmaxf(y2 - y1, 0.f);
            float inter = w * h;
            float uni = fmaf(inter, -INV_L2E, ar0 + ax.x);   // ln2*union
            float iou = inter * __builtin_amdgcn_rcpf(uni);  // iou*log2e
            float e0 = EXP2F(fmaf(p0v0.x, pj.x, iou));
            float e1 = EXP2F(fmaf(p0v0.y, pj.y, iou));
            float e2 = EXP2F(fmaf(p0v0.z, pj.z, iou));
            n00 = fmaf(e0, ax.y, n00); d00 += e0;
            n01 = fmaf(e1, ax.z, n01); d01 += e1;
            n02 = fmaf(e2, ax.w, n02); d02 += e2;
        }
        {   // row 1
            float x1 = fmaxf(bx1.x, bj.x), y1 = fmaxf(bx1.y, bj.y);
            float x2 = fminf(bx1.z, bj.z), y2 = fminf(bx1.w, bj.w);
            float w = fmaxf(x2 - x1, 0.f), h = fmaxf(y2 - y1, 0.f);
            float inter = w * h;
            float uni = fmaf(inter, -INV_L2E, ar1 + ax.x);
            float iou = inter * __builtin_amdgcn_rcpf(uni);
            float e0 = EXP2F(fmaf(p0v1.x, pj.x, iou));
            float e1 = EXP2F(fmaf(p0v1.y, pj.y, iou));
            float e2 = EXP2F(fmaf(p0v1.z, pj.z, iou));
            n10 = fmaf(e0, ax.y, n10); d10 += e0;
            n11 = fmaf(e1, ax.z, n11); d11 += e1;
            n12 = fmaf(e2, ax.w, n12); d12 += e2;
        }
    }

    s_m[0][r][q] = make_float2(n00, d00);
    s_m[1][r][q] = make_float2(n01, d01);
    s_m[2][r][q] = make_float2(n02, d02);
    s_m[0][r + 64][q] = make_float2(n10, d10);
    s_m[1][r + 64][q] = make_float2(n11, d11);
    s_m[2][r + 64][q] = make_float2(n12, d12);
    __syncthreads();

    float2* part = (float2*)(ws + WS_PART);
    for (int u = t; u < C_ * ROWBLK; u += 256) {
        const int c = u >> 7, row = u & 127;
        float2 a0 = s_m[c][row][0], a1 = s_m[c][row][1];
        float2 a2 = s_m[c][row][2], a3 = s_m[c][row][3];
        part[((b * JSPLIT + jb) * C_ + c) * N_ + rowblk * ROWBLK + row] =
            make_float2(a0.x + a1.x + a2.x + a3.x, a0.y + a1.y + a2.y + a3.y);
    }
}

// grid 96 blocks x 256: one thread per (b,c,row). Block recomputes S_bc
// (score-softmax denominator) from raw scores (16 exps/thread + reduction),
// then sums 16 j-partials, divides, writes output 0.
__global__ __launch_bounds__(256) void k_reduce(
    const float* __restrict__ scores, const float* __restrict__ ws,
    float* __restrict__ out)
{
    const int t = threadIdx.x;
    const int tid = blockIdx.x * 256 + t;   // 0..24575
    const int bc = tid >> 12;               // uniform per block (4096 % 256 == 0)
    const int i  = tid & 4095;
    const int b = bc / C_, c = bc % C_;

    __shared__ float red[4];
    const float* scb = scores + (b * AC_ + c) * HW_;
    float ls = 0.f;
    for (int n = t; n < N_; n += 256)
        ls += __expf(scb[(n & 3) * 3 * HW_ + (n >> 2)]);
#pragma unroll
    for (int off = 1; off < 64; off <<= 1) ls += __shfl_xor(ls, off);
    if ((t & 63) == 0) red[t >> 6] = ls;
    __syncthreads();
    const float S = red[0] + red[1] + red[2] + red[3];

    const float2* part = (const float2*)(ws + WS_PART);
    float num = 0.f, den = 0.f;
#pragma unroll
    for (int jb = 0; jb < JSPLIT; ++jb) {
        float2 v = part[((b * JSPLIT + jb) * C_ + c) * N_ + i];
        num += v.x; den += v.y;
    }
    out[(b * AC_ + (i & 3) * 3 + c) * HW_ + (i >> 2)] = num / (den * S);
}

extern "C" void kernel_launch(void* const* d_in, const int* in_sizes, int n_in,
                              void* d_out, int out_size, void* d_ws, size_t ws_size,
                              hipStream_t stream) {
    const float* scores = (const float*)d_in[0];
    const float* bbox   = (const float*)d_in[1];
    const float* pp     = (const float*)d_in[2];
    const float* dec    = (const float*)d_in[3];
    float* out = (float*)d_out;
    float* ws  = (float*)d_ws;

    k_main<<<dim3(MAINBLKS + CPBLKS, B_), 256, 0, stream>>>(scores, pp, dec, bbox, ws, out);
    k_reduce<<<OUT0_ELEMS / 256, 256, 0, stream>>>(scores, ws, out);
}

// Round 6
// 94.625 us; speedup vs baseline: 1.0123x; 1.0123x over previous
//
#include <hip/hip_runtime.h>
#include <math.h>

#define B_   2
#define C_   3
#define HW_  1024
#define N_   4096
#define AC_  12
#define JSPLIT 32
#define JTILE  128
#define ROWBLK 128
#define PI_F 3.14159265358979323846f
#define L2E     1.4426950408889634f   // log2(e)
#define INV_L2E 0.6931471805599453f   // ln(2)

#define OUT0_ELEMS 24576   // B*A*C*H*W
#define OUT1_ELEMS 57344   // B*A*7*H*W
#define OUT2_ELEMS 18432   // B*C*3*H*W

// ws layout (float units), SoA per (b,n):
//   jbox:  float4[2][4096]  {x1,y1,x2,y2}                       @ 0
//   jaux:  float4[2][4096]  {area*ln2, e_c0, e_c1, e_c2}        @ 32768
//   jp1:   float4[2][4096]  {p1_c0, p1_c1, p1_c2, 0}            @ 65536
//   jp0:   float4[2][4096]  {p0_c0*l2e, p0_c1*l2e, p0_c2*l2e,0} @ 98304
//   part:  float2[2][32][3][4096]                               @ 131072
//   stats: float [6][8]                                         @ 1703936
#define WS_JBOX  0
#define WS_JAUX  32768
#define WS_JP1   65536
#define WS_JP0   98304
#define WS_PART  131072
#define WS_STATS 1703936

#if __has_builtin(__builtin_amdgcn_exp2f)
#define EXP2F(x) __builtin_amdgcn_exp2f(x)
#else
#define EXP2F(x) __expf((x) * INV_L2E)
#endif

#define PREP_JBLKS 16           // 2 b * 8 segments
#define PREP_CPBLKS 80
#define CP_F4_BBOX 14336        // OUT1_ELEMS/4
#define CP_F4_TOT  18944        // (OUT1+OUT2)/4

// Decode one row of `decoded` into a BEV corner box (x1,y1,x2,y2).
__device__ __forceinline__ float4 make_box(const float* __restrict__ d) {
    float x = d[0], y = d[1], d3 = d[3], d4 = d[4], rot = d[6];
    float kq = floorf(rot / PI_F + 0.5f);
    float normed = fabsf(rot - kq * PI_F);
    bool swap_wh = normed > (0.25f * PI_F);
    float w = swap_wh ? d4 : d3;
    float h = swap_wh ? d3 : d4;
    return make_float4(x - 0.5f * w, y - 0.5f * h, x + 0.5f * w, y + 0.5f * h);
}

// grid 96 blocks x 256:
//   blocks [0,16):  jdata (boxes shared across classes) + partial softmax
//                   denominators for all 3 classes of (b, seg)
//   blocks [16,96): passthrough copies (outputs 1 and 2) as float4
// Softmax max-shifts dropped: they cancel in num/(den*S); values safe in f32.
__global__ __launch_bounds__(256) void k_prep(
    const float* __restrict__ scores, const float* __restrict__ pp,
    const float* __restrict__ dec, const float* __restrict__ bbox,
    float* __restrict__ ws, float* __restrict__ out)
{
    const int blk = blockIdx.x;
    const int t = threadIdx.x;

    if (blk >= PREP_JBLKS) {
        const float4* src1 = (const float4*)bbox;
        const float4* src2 = (const float4*)pp;
        float4* dst1 = (float4*)(out + OUT0_ELEMS);
        float4* dst2 = (float4*)(out + OUT0_ELEMS + OUT1_ELEMS);
        for (int u = (blk - PREP_JBLKS) * 256 + t; u < CP_F4_TOT;
             u += PREP_CPBLKS * 256) {
            if (u < CP_F4_BBOX) dst1[u] = src1[u];
            else                dst2[u - CP_F4_BBOX] = src2[u - CP_F4_BBOX];
        }
        return;
    }

    const int b = blk >> 3, seg = blk & 7;
    const float* decb = dec + b * N_ * 7;
    float4* jbox = (float4*)(ws + WS_JBOX) + b * N_;
    float4* jaux = (float4*)(ws + WS_JAUX) + b * N_;
    float4* jp1  = (float4*)(ws + WS_JP1)  + b * N_;
    float4* jp0  = (float4*)(ws + WS_JP0)  + b * N_;

    __shared__ float red[4][3];
    float ls0 = 0.f, ls1 = 0.f, ls2 = 0.f;
    const int n0 = seg * 512;
    for (int n = n0 + t; n < n0 + 512; n += 256) {
        const int hw = n >> 2, a = n & 3;
        float4 box = make_box(decb + n * 7);
        float area = (box.z - box.x) * (box.w - box.y);
        float e0 = __expf(scores[(b * AC_ + a * C_ + 0) * HW_ + hw]);
        float e1 = __expf(scores[(b * AC_ + a * C_ + 1) * HW_ + hw]);
        float e2 = __expf(scores[(b * AC_ + a * C_ + 2) * HW_ + hw]);
        ls0 += e0; ls1 += e1; ls2 += e2;
        jbox[n] = box;
        jaux[n] = make_float4(area * INV_L2E, e0, e1, e2);
        jp1[n]  = make_float4(pp[(b * 9 + 1) * HW_ + hw],
                              pp[(b * 9 + 4) * HW_ + hw],
                              pp[(b * 9 + 7) * HW_ + hw], 0.f);
        jp0[n]  = make_float4(pp[(b * 9 + 0) * HW_ + hw] * L2E,
                              pp[(b * 9 + 3) * HW_ + hw] * L2E,
                              pp[(b * 9 + 6) * HW_ + hw] * L2E, 0.f);
    }
#pragma unroll
    for (int off = 1; off < 64; off <<= 1) {
        ls0 += __shfl_xor(ls0, off);
        ls1 += __shfl_xor(ls1, off);
        ls2 += __shfl_xor(ls2, off);
    }
    if ((t & 63) == 0) { red[t >> 6][0] = ls0; red[t >> 6][1] = ls1; red[t >> 6][2] = ls2; }
    __syncthreads();
    if (t < 3)
        ws[WS_STATS + (b * C_ + t) * 8 + seg] =
            red[0][t] + red[1][t] + red[2][t] + red[3][t];
}

// grid (32 rowblks * 32 jblks, B_), 256 threads. 8 blocks/CU (18.4 KB LDS),
// 32 waves/CU — max occupancy to hide the quarter-rate exp chains.
// Block: 128 rows x 128 j's of one b, ALL 3 CLASSES at once — the IoU core
// (incl. v_rcp) is computed once per (i,j) and shared across classes.
// Thread owns 2 rows + a j-quarter (quarter == wave -> LDS broadcast reads).
__global__ __launch_bounds__(256) void k_main(float* __restrict__ ws)
{
    const int b = blockIdx.y;
    const int jb = blockIdx.x & 31;
    const int rowblk = blockIdx.x >> 5;
    const int t = threadIdx.x;
    const int q = t >> 6;   // wave index == j-quarter
    const int r = t & 63;

    const float4* jbox = (const float4*)(ws + WS_JBOX) + b * N_;
    const float4* jaux = (const float4*)(ws + WS_JAUX) + b * N_;
    const float4* jp1  = (const float4*)(ws + WS_JP1)  + b * N_;
    const float4* jp0  = (const float4*)(ws + WS_JP0)  + b * N_;

    __shared__ float4 s_box[JTILE];
    __shared__ float4 s_aux[JTILE];
    __shared__ float4 s_p1[JTILE];
    __shared__ float2 s_m[C_][ROWBLK][4];

    // stage j-tile (coalesced; threads t<128 each load 3 float4s)
    const int jbase = jb * JTILE;
    if (t < JTILE) {
        s_box[t] = jbox[jbase + t];
        s_aux[t] = jaux[jbase + t];
        s_p1[t]  = jp1[jbase + t];
    }

    // row setup
    const int i0 = rowblk * ROWBLK + r, i1 = i0 + 64;
    const float4 bx0 = jbox[i0], bx1 = jbox[i1];
    const float  ar0 = jaux[i0].x, ar1 = jaux[i1].x;   // area*ln2
    const float4 p0v0 = jp0[i0], p0v1 = jp0[i1];       // p0_c * log2e

    __syncthreads();

    float n00 = 0.f, d00 = 0.f, n01 = 0.f, d01 = 0.f, n02 = 0.f, d02 = 0.f;
    float n10 = 0.f, d10 = 0.f, n11 = 0.f, d11 = 0.f, n12 = 0.f, d12 = 0.f;

#pragma unroll 4
    for (int jj = q; jj < JTILE; jj += 4) {
        const float4 bj = s_box[jj];
        const float4 ax = s_aux[jj];   // {area_j*ln2, e0, e1, e2}
        const float4 pj = s_p1[jj];    // {p1_0, p1_1, p1_2, -}
        {   // row 0: shared IoU, 3-class tail
            float x1 = fmaxf(bx0.x, bj.x), y1 = fmaxf(bx0.y, bj.y);
            float x2 = fminf(bx0.z, bj.z), y2 = fminf(bx0.w, bj.w);
            float w = fmaxf(x2 - x1, 0.f), h = fmaxf(y2 - y1, 0.f);
            float inter = w * h;
            float uni = fmaf(inter, -INV_L2E, ar0 + ax.x);   // ln2*union
            float iou = inter * __builtin_amdgcn_rcpf(uni);  // iou*log2e
            float e0 = EXP2F(fmaf(p0v0.x, pj.x, iou));
            float e1 = EXP2F(fmaf(p0v0.y, pj.y, iou));
            float e2 = EXP2F(fmaf(p0v0.z, pj.z, iou));
            n00 = fmaf(e0, ax.y, n00); d00 += e0;
            n01 = fmaf(e1, ax.z, n01); d01 += e1;
            n02 = fmaf(e2, ax.w, n02); d02 += e2;
        }
        {   // row 1
            float x1 = fmaxf(bx1.x, bj.x), y1 = fmaxf(bx1.y, bj.y);
            float x2 = fminf(bx1.z, bj.z), y2 = fminf(bx1.w, bj.w);
            float w = fmaxf(x2 - x1, 0.f), h = fmaxf(y2 - y1, 0.f);
            float inter = w * h;
            float uni = fmaf(inter, -INV_L2E, ar1 + ax.x);
            float iou = inter * __builtin_amdgcn_rcpf(uni);
            float e0 = EXP2F(fmaf(p0v1.x, pj.x, iou));
            float e1 = EXP2F(fmaf(p0v1.y, pj.y, iou));
            float e2 = EXP2F(fmaf(p0v1.z, pj.z, iou));
            n10 = fmaf(e0, ax.y, n10); d10 += e0;
            n11 = fmaf(e1, ax.z, n11); d11 += e1;
            n12 = fmaf(e2, ax.w, n12); d12 += e2;
        }
    }

    s_m[0][r][q] = make_float2(n00, d00);
    s_m[1][r][q] = make_float2(n01, d01);
    s_m[2][r][q] = make_float2(n02, d02);
    s_m[0][r + 64][q] = make_float2(n10, d10);
    s_m[1][r + 64][q] = make_float2(n11, d11);
    s_m[2][r + 64][q] = make_float2(n12, d12);
    __syncthreads();

    float2* part = (float2*)(ws + WS_PART);
    for (int u = t; u < C_ * ROWBLK; u += 256) {
        const int c = u >> 7, row = u & 127;
        float2 a0 = s_m[c][row][0], a1 = s_m[c][row][1];
        float2 a2 = s_m[c][row][2], a3 = s_m[c][row][3];
        part[((b * JSPLIT + jb) * C_ + c) * N_ + rowblk * ROWBLK + row] =
            make_float2(a0.x + a1.x + a2.x + a3.x, a0.y + a1.y + a2.y + a3.y);
    }
}

// grid 96 blocks x 256: one thread per (b,c,row). Sums 32 j-partials + 8
// S-partials (L1 broadcast), divides, writes output 0.
__global__ __launch_bounds__(256) void k_reduce(
    const float* __restrict__ ws, float* __restrict__ out)
{
    const int tid = blockIdx.x * 256 + threadIdx.x;   // 0..24575
    const int bc = tid >> 12;
    const int i  = tid & 4095;
    const int b = bc / C_, c = bc % C_;
    const float2* part = (const float2*)(ws + WS_PART);
    float num = 0.f, den = 0.f;
#pragma unroll
    for (int jb = 0; jb < JSPLIT; ++jb) {
        float2 v = part[((b * JSPLIT + jb) * C_ + c) * N_ + i];
        num += v.x; den += v.y;
    }
    float S = 0.f;
#pragma unroll
    for (int s = 0; s < 8; ++s) S += ws[WS_STATS + bc * 8 + s];
    out[(b * AC_ + (i & 3) * 3 + c) * HW_ + (i >> 2)] = num / (den * S);
}

extern "C" void kernel_launch(void* const* d_in, const int* in_sizes, int n_in,
                              void* d_out, int out_size, void* d_ws, size_t ws_size,
                              hipStream_t stream) {
    const float* scores = (const float*)d_in[0];
    const float* bbox   = (const float*)d_in[1];
    const float* pp     = (const float*)d_in[2];
    const float* dec    = (const float*)d_in[3];
    float* out = (float*)d_out;
    float* ws  = (float*)d_ws;

    k_prep<<<PREP_JBLKS + PREP_CPBLKS, 256, 0, stream>>>(scores, pp, dec, bbox, ws, out);
    k_main<<<dim3(32 * JSPLIT, B_), 256, 0, stream>>>(ws);
    k_reduce<<<OUT0_ELEMS / 256, 256, 0, stream>>>(ws, out);
}

// Round 7
// 93.430 us; speedup vs baseline: 1.0252x; 1.0128x over previous
//
#include <hip/hip_runtime.h>
#include <math.h>

#define B_   2
#define C_   3
#define HW_  1024
#define N_   4096
#define AC_  12
#define JSPLIT 16
#define JTILE  256
#define ROWBLK 128
#define PI_F 3.14159265358979323846f
#define L2E     1.4426950408889634f   // log2(e)
#define INV_L2E 0.6931471805599453f   // ln(2)

#define OUT0_ELEMS 24576   // B*A*C*H*W
#define OUT1_ELEMS 57344   // B*A*7*H*W
#define OUT2_ELEMS 18432   // B*C*3*H*W

// ws layout (float units), SoA per (b,n):
//   jbox:  float4[2][4096]  {x1,y1,x2,y2}                       @ 0
//   jaux:  float4[2][4096]  {area*ln2, e_c0, e_c1, e_c2}        @ 32768
//   jp1:   float4[2][4096]  {p1_c0, p1_c1, p1_c2, 0}            @ 65536
//   jp0:   float4[2][4096]  {p0_c0*l2e, p0_c1*l2e, p0_c2*l2e,0} @ 98304
//   part:  float2[2][16][3][4096]                               @ 131072
//   stats: float [6][8]                                         @ 917504
#define WS_JBOX  0
#define WS_JAUX  32768
#define WS_JP1   65536
#define WS_JP0   98304
#define WS_PART  131072
#define WS_STATS 917504

#if __has_builtin(__builtin_amdgcn_exp2f)
#define EXP2F(x) __builtin_amdgcn_exp2f(x)
#else
#define EXP2F(x) __expf((x) * INV_L2E)
#endif

#define PREP_JBLKS 16           // 2 b * 8 segments
#define PREP_CPBLKS 80
#define CP_F4_BBOX 14336        // OUT1_ELEMS/4
#define CP_F4_TOT  18944        // (OUT1+OUT2)/4

// Decode one row of `decoded` into a BEV corner box (x1,y1,x2,y2).
__device__ __forceinline__ float4 make_box(const float* __restrict__ d) {
    float x = d[0], y = d[1], d3 = d[3], d4 = d[4], rot = d[6];
    float kq = floorf(rot / PI_F + 0.5f);
    float normed = fabsf(rot - kq * PI_F);
    bool swap_wh = normed > (0.25f * PI_F);
    float w = swap_wh ? d4 : d3;
    float h = swap_wh ? d3 : d4;
    return make_float4(x - 0.5f * w, y - 0.5f * h, x + 0.5f * w, y + 0.5f * h);
}

// grid 96 blocks x 256:
//   blocks [0,16):  jdata (boxes shared across classes) + partial softmax
//                   denominators for all 3 classes of (b, seg)
//   blocks [16,96): passthrough copies (outputs 1 and 2) as float4
// Softmax max-shifts dropped: they cancel in num/(den*S); values safe in f32.
__global__ __launch_bounds__(256) void k_prep(
    const float* __restrict__ scores, const float* __restrict__ pp,
    const float* __restrict__ dec, const float* __restrict__ bbox,
    float* __restrict__ ws, float* __restrict__ out)
{
    const int blk = blockIdx.x;
    const int t = threadIdx.x;

    if (blk >= PREP_JBLKS) {
        const float4* src1 = (const float4*)bbox;
        const float4* src2 = (const float4*)pp;
        float4* dst1 = (float4*)(out + OUT0_ELEMS);
        float4* dst2 = (float4*)(out + OUT0_ELEMS + OUT1_ELEMS);
        for (int u = (blk - PREP_JBLKS) * 256 + t; u < CP_F4_TOT;
             u += PREP_CPBLKS * 256) {
            if (u < CP_F4_BBOX) dst1[u] = src1[u];
            else                dst2[u - CP_F4_BBOX] = src2[u - CP_F4_BBOX];
        }
        return;
    }

    const int b = blk >> 3, seg = blk & 7;
    const float* decb = dec + b * N_ * 7;
    float4* jbox = (float4*)(ws + WS_JBOX) + b * N_;
    float4* jaux = (float4*)(ws + WS_JAUX) + b * N_;
    float4* jp1  = (float4*)(ws + WS_JP1)  + b * N_;
    float4* jp0  = (float4*)(ws + WS_JP0)  + b * N_;

    __shared__ float red[4][3];
    float ls0 = 0.f, ls1 = 0.f, ls2 = 0.f;
    const int n0 = seg * 512;
    for (int n = n0 + t; n < n0 + 512; n += 256) {
        const int hw = n >> 2, a = n & 3;
        float4 box = make_box(decb + n * 7);
        float area = (box.z - box.x) * (box.w - box.y);
        float e0 = __expf(scores[(b * AC_ + a * C_ + 0) * HW_ + hw]);
        float e1 = __expf(scores[(b * AC_ + a * C_ + 1) * HW_ + hw]);
        float e2 = __expf(scores[(b * AC_ + a * C_ + 2) * HW_ + hw]);
        ls0 += e0; ls1 += e1; ls2 += e2;
        jbox[n] = box;
        jaux[n] = make_float4(area * INV_L2E, e0, e1, e2);
        jp1[n]  = make_float4(pp[(b * 9 + 1) * HW_ + hw],
                              pp[(b * 9 + 4) * HW_ + hw],
                              pp[(b * 9 + 7) * HW_ + hw], 0.f);
        jp0[n]  = make_float4(pp[(b * 9 + 0) * HW_ + hw] * L2E,
                              pp[(b * 9 + 3) * HW_ + hw] * L2E,
                              pp[(b * 9 + 6) * HW_ + hw] * L2E, 0.f);
    }
#pragma unroll
    for (int off = 1; off < 64; off <<= 1) {
        ls0 += __shfl_xor(ls0, off);
        ls1 += __shfl_xor(ls1, off);
        ls2 += __shfl_xor(ls2, off);
    }
    if ((t & 63) == 0) { red[t >> 6][0] = ls0; red[t >> 6][1] = ls1; red[t >> 6][2] = ls2; }
    __syncthreads();
    if (t < 3)
        ws[WS_STATS + (b * C_ + t) * 8 + seg] =
            red[0][t] + red[1][t] + red[2][t] + red[3][t];
}

// grid (32 rowblks * 16 jblks, B_), 256 threads.
// Block: 128 rows x 256 j's of one b, ALL 3 CLASSES at once — the IoU core
// (incl. v_rcp) is computed once per (i,j) and shared across classes; only
// fma+exp2+2 accums are per-class. Thread owns 2 rows + a j-quarter
// (quarter == wave index -> LDS broadcast reads).
// Measured (R4): VALUBusy ~86% -> issue-bound; occupancy doubling (R6) and
// kernel fusion (R5) both failed to beat this configuration.
__global__ __launch_bounds__(256) void k_main(float* __restrict__ ws)
{
    const int b = blockIdx.y;
    const int jb = blockIdx.x & 15;
    const int rowblk = blockIdx.x >> 4;
    const int t = threadIdx.x;
    const int q = t >> 6;   // wave index == j-quarter
    const int r = t & 63;

    const float4* jbox = (const float4*)(ws + WS_JBOX) + b * N_;
    const float4* jaux = (const float4*)(ws + WS_JAUX) + b * N_;
    const float4* jp1  = (const float4*)(ws + WS_JP1)  + b * N_;
    const float4* jp0  = (const float4*)(ws + WS_JP0)  + b * N_;

    __shared__ float4 s_box[JTILE];
    __shared__ float4 s_aux[JTILE];
    __shared__ float4 s_p1[JTILE];
    __shared__ float2 s_m[C_][ROWBLK][4];

    // stage j-tile (coalesced: one float4 per thread per array)
    const int jbase = jb * JTILE;
    s_box[t] = jbox[jbase + t];
    s_aux[t] = jaux[jbase + t];
    s_p1[t]  = jp1[jbase + t];

    // row setup
    const int i0 = rowblk * ROWBLK + r, i1 = i0 + 64;
    const float4 bx0 = jbox[i0], bx1 = jbox[i1];
    const float  ar0 = jaux[i0].x, ar1 = jaux[i1].x;   // area*ln2
    const float4 p0v0 = jp0[i0], p0v1 = jp0[i1];       // p0_c * log2e

    __syncthreads();

    float n00 = 0.f, d00 = 0.f, n01 = 0.f, d01 = 0.f, n02 = 0.f, d02 = 0.f;
    float n10 = 0.f, d10 = 0.f, n11 = 0.f, d11 = 0.f, n12 = 0.f, d12 = 0.f;

#pragma unroll 4
    for (int jj = q; jj < JTILE; jj += 4) {
        const float4 bj = s_box[jj];
        const float4 ax = s_aux[jj];   // {area_j*ln2, e0, e1, e2}
        const float4 pj = s_p1[jj];    // {p1_0, p1_1, p1_2, -}
        {   // row 0: shared IoU, 3-class tail
            float x1 = fmaxf(bx0.x, bj.x), y1 = fmaxf(bx0.y, bj.y);
            float x2 = fminf(bx0.z, bj.z), y2 = fminf(bx0.w, bj.w);
            float w = fmaxf(x2 - x1, 0.f), h = fmaxf(y2 - y1, 0.f);
            float inter = w * h;
            float uni = fmaf(inter, -INV_L2E, ar0 + ax.x);   // ln2*union
            float iou = inter * __builtin_amdgcn_rcpf(uni);  // iou*log2e
            float e0 = EXP2F(fmaf(p0v0.x, pj.x, iou));
            float e1 = EXP2F(fmaf(p0v0.y, pj.y, iou));
            float e2 = EXP2F(fmaf(p0v0.z, pj.z, iou));
            n00 = fmaf(e0, ax.y, n00); d00 += e0;
            n01 = fmaf(e1, ax.z, n01); d01 += e1;
            n02 = fmaf(e2, ax.w, n02); d02 += e2;
        }
        {   // row 1
            float x1 = fmaxf(bx1.x, bj.x), y1 = fmaxf(bx1.y, bj.y);
            float x2 = fminf(bx1.z, bj.z), y2 = fminf(bx1.w, bj.w);
            float w = fmaxf(x2 - x1, 0.f), h = fmaxf(y2 - y1, 0.f);
            float inter = w * h;
            float uni = fmaf(inter, -INV_L2E, ar1 + ax.x);
            float iou = inter * __builtin_amdgcn_rcpf(uni);
            float e0 = EXP2F(fmaf(p0v1.x, pj.x, iou));
            float e1 = EXP2F(fmaf(p0v1.y, pj.y, iou));
            float e2 = EXP2F(fmaf(p0v1.z, pj.z, iou));
            n10 = fmaf(e0, ax.y, n10); d10 += e0;
            n11 = fmaf(e1, ax.z, n11); d11 += e1;
            n12 = fmaf(e2, ax.w, n12); d12 += e2;
        }
    }

    s_m[0][r][q] = make_float2(n00, d00);
    s_m[1][r][q] = make_float2(n01, d01);
    s_m[2][r][q] = make_float2(n02, d02);
    s_m[0][r + 64][q] = make_float2(n10, d10);
    s_m[1][r + 64][q] = make_float2(n11, d11);
    s_m[2][r + 64][q] = make_float2(n12, d12);
    __syncthreads();

    float2* part = (float2*)(ws + WS_PART);
    for (int u = t; u < C_ * ROWBLK; u += 256) {
        const int c = u >> 7, row = u & 127;
        float2 a0 = s_m[c][row][0], a1 = s_m[c][row][1];
        float2 a2 = s_m[c][row][2], a3 = s_m[c][row][3];
        part[((b * JSPLIT + jb) * C_ + c) * N_ + rowblk * ROWBLK + row] =
            make_float2(a0.x + a1.x + a2.x + a3.x, a0.y + a1.y + a2.y + a3.y);
    }
}

// grid 96 blocks x 256: one thread per (b,c,row). Sums 16 j-partials + 8
// S-partials (L1 broadcast), divides, writes output 0.
__global__ __launch_bounds__(256) void k_reduce(
    const float* __restrict__ ws, float* __restrict__ out)
{
    const int tid = blockIdx.x * 256 + threadIdx.x;   // 0..24575
    const int bc = tid >> 12;
    const int i  = tid & 4095;
    const int b = bc / C_, c = bc % C_;
    const float2* part = (const float2*)(ws + WS_PART);
    float num = 0.f, den = 0.f;
#pragma unroll
    for (int jb = 0; jb < JSPLIT; ++jb) {
        float2 v = part[((b * JSPLIT + jb) * C_ + c) * N_ + i];
        num += v.x; den += v.y;
    }
    float S = 0.f;
#pragma unroll
    for (int s = 0; s < 8; ++s) S += ws[WS_STATS + bc * 8 + s];
    out[(b * AC_ + (i & 3) * 3 + c) * HW_ + (i >> 2)] = num / (den * S);
}

extern "C" void kernel_launch(void* const* d_in, const int* in_sizes, int n_in,
                              void* d_out, int out_size, void* d_ws, size_t ws_size,
                              hipStream_t stream) {
    const float* scores = (const float*)d_in[0];
    const float* bbox   = (const float*)d_in[1];
    const float* pp     = (const float*)d_in[2];
    const float* dec    = (const float*)d_in[3];
    float* out = (float*)d_out;
    float* ws  = (float*)d_ws;

    k_prep<<<PREP_JBLKS + PREP_CPBLKS, 256, 0, stream>>>(scores, pp, dec, bbox, ws, out);
    k_main<<<dim3(32 * JSPLIT, B_), 256, 0, stream>>>(ws);
    k_reduce<<<OUT0_ELEMS / 256, 256, 0, stream>>>(ws, out);
}